// Round 8
// baseline (488.383 us; speedup 1.0000x reference)
//
#include <hip/hip_runtime.h>
#include <hip/hip_bf16.h>

#define NG 100000
#define ND 50000
#define NC 2000
#define NF 5000
#define DD 64

#define BSH 9
#define BINW 512
#define NREL 6
#define NB_CG ((NG + BINW - 1) / BINW)
#define NB_GC ((ND + BINW - 1) / BINW)
#define NB_CP ((NC + BINW - 1) / BINW)
#define NB_PC ((ND + BINW - 1) / BINW)
#define NB_GF ((NF + BINW - 1) / BINW)
#define NB_FG ((NG + BINW - 1) / BINW)
#define TOTB (NB_CG + NB_GC + NB_CP + NB_PC + NB_GF + NB_FG)
#define CHUNK 4096

typedef _Float16 h2_t __attribute__((ext_vector_type(2)));
typedef _Float16 half8 __attribute__((ext_vector_type(8)));
typedef float f32x4 __attribute__((ext_vector_type(4)));

__device__ inline uint packh2_rne(float a, float b) {
    h2_t h; h.x = (_Float16)a; h.y = (_Float16)b;
    return __builtin_bit_cast(uint, h);
}
__device__ inline float2 h2f2(uint u) {
    h2_t h = __builtin_bit_cast(h2_t, u);
    return make_float2((float)h.x, (float)h.y);
}
__device__ inline float fdot2u(uint m, uint w, float acc) {
#if __has_builtin(__builtin_amdgcn_fdot2)
    return __builtin_amdgcn_fdot2(__builtin_bit_cast(h2_t, m),
                                  __builtin_bit_cast(h2_t, w), acc, false);
#else
    float2 a = h2f2(m), b = h2f2(w);
    return acc + a.x * b.x + a.y * b.y;
#endif
}

// ---------------------------------------------------------------------------
struct Cvt4 { const float* in[4]; uint* out[4]; int n2[4]; };
struct EdgeJobs {
    const int* src[NREL]; const int* dst[NREL];
    int binbase[NREL]; int E[NREL]; int blk_end[NREL];
};
struct BPackJobs {
    const float* A[6]; const float* B[6]; const float* Ra[6]; const float* Rb[6];
    uint4* out[6]; int nkt[6];
};

// ---------------------------------------------------------------------------
// Mega pass A: edge bin-histogram | f32->f16 table cvt | Wc1 dot2 pack |
// MFMA B-image packs.
struct MegaA {
    EdgeJobs ej; Cvt4 cv; BPackJobs bp;
    const float* Wc1; uint2* pwWc1;
    int hist_blocks, cvt_blocks;
    int* ghist;
};
__global__ __launch_bounds__(256) void megaA_kernel(MegaA a) {
    int b = blockIdx.x;
    if (b < a.hist_blocks) {
        __shared__ int lh[TOTB];
        for (int t = threadIdx.x; t < TOTB; t += 256) lh[t] = 0;
        __syncthreads();
        int j = 0;
        while (b >= a.ej.blk_end[j]) ++j;
        int b0 = j ? a.ej.blk_end[j - 1] : 0;
        int e0 = (b - b0) * CHUNK;
        const int* dst = a.ej.dst[j];
        int E = a.ej.E[j], bb = a.ej.binbase[j];
        for (int t = threadIdx.x; t < CHUNK; t += 256) {
            int e = e0 + t;
            if (e < E) atomicAdd(&lh[bb + (dst[e] >> BSH)], 1);
        }
        __syncthreads();
        for (int t = threadIdx.x; t < TOTB; t += 256)
            if (lh[t]) atomicAdd(&a.ghist[t], lh[t]);
    } else if (b < a.hist_blocks + a.cvt_blocks) {
        int cb = b - a.hist_blocks;
        for (int j = 0; j < 4; ++j) {
            int n2 = a.cv.n2[j];
            const float2* ip = (const float2*)a.cv.in[j];
            uint* op = a.cv.out[j];
            for (int i = cb * 256 + threadIdx.x; i < n2; i += a.cvt_blocks * 256)
                op[i] = packh2_rne(ip[i].x, ip[i].y);
        }
    } else if (b == a.hist_blocks + a.cvt_blocks) {
        const float* A = a.Wc1;
        uint2* o = a.pwWc1;
        for (int t = threadIdx.x; t < 32 * 64; t += 256) {
            int k4 = t >> 6, c = t & 63;
            float v0 = A[(4 * k4 + 0) * 64 + c];
            float v1 = A[(4 * k4 + 1) * 64 + c];
            float v2 = A[(4 * k4 + 2) * 64 + c];
            float v3 = A[(4 * k4 + 3) * 64 + c];
            o[t] = make_uint2(packh2_rne(v0, v1), packh2_rne(v2, v3));
        }
    } else {
        int pj = b - a.hist_blocks - a.cvt_blocks - 1;
        const float* A = a.bp.A[pj];
        const float* B = a.bp.B[pj];
        const float* Ra = a.bp.Ra[pj];
        const float* Rb = a.bp.Rb[pj];
        uint4* o = a.bp.out[pj];
        int n = a.bp.nkt[pj] * 4 * 64;
        for (int t = threadIdx.x; t < n; t += 256) {
            int kt = t >> 8, nt = (t >> 6) & 3, l = t & 63;
            int col = nt * 16 + (l & 15);
            float v[8];
#pragma unroll
            for (int j = 0; j < 8; ++j) {
                int k = kt * 32 + ((l >> 4) << 3) + j;
                int sel = k >> 6, r = k & 63;
                float x;
                if (sel == 0) x = A[r * 64 + col];
                else if (sel == 1 && B) x = B[r * 64 + col];
                else x = Ra[r * 64 + col] + (Rb ? Rb[r * 64 + col] : 0.f);
                v[j] = x;
            }
            o[t] = make_uint4(packh2_rne(v[0], v[1]), packh2_rne(v[2], v[3]),
                              packh2_rne(v[4], v[5]), packh2_rne(v[6], v[7]));
        }
    }
}

// ---------------------------------------------------------------------------
// Pass B: exclusive scan of bin counts (1 block, wave 0)
__global__ void scanB_kernel(const int* __restrict__ ghist, int* __restrict__ gbinstart,
                             int* __restrict__ gcursor) {
    int lane = threadIdx.x;
    if (lane >= 64) return;
    int carry = 0;
    for (int base = 0; base < TOTB; base += 64) {
        int idx = base + lane;
        int v = (idx < TOTB) ? ghist[idx] : 0;
        int ts = v;
        for (int d = 1; d < 64; d <<= 1) { int t = __shfl_up(ts, d); if (lane >= d) ts += t; }
        int excl = carry + ts - v;
        if (idx < TOTB) { gbinstart[idx] = excl; gcursor[idx] = excl; }
        carry += __shfl(ts, 63);
    }
    if (lane == 0) gbinstart[TOTB] = carry;
}

// ---------------------------------------------------------------------------
// Pass C: binned scatter of packed (src<<9 | dstLocal)
__global__ __launch_bounds__(256) void scatC_kernel(EdgeJobs ej, int* __restrict__ gcursor,
                                                    int* __restrict__ binned) {
    __shared__ int lh[TOTB], lbase[TOTB];
    for (int t = threadIdx.x; t < TOTB; t += 256) lh[t] = 0;
    __syncthreads();
    int b = blockIdx.x, j = 0;
    while (b >= ej.blk_end[j]) ++j;
    int b0 = j ? ej.blk_end[j - 1] : 0;
    int e0 = (b - b0) * CHUNK;
    const int* dst = ej.dst[j];
    const int* srcp = ej.src[j];
    int E = ej.E[j], bb = ej.binbase[j];
    for (int t = threadIdx.x; t < CHUNK; t += 256) {
        int e = e0 + t;
        if (e < E) atomicAdd(&lh[bb + (dst[e] >> BSH)], 1);
    }
    __syncthreads();
    for (int t = threadIdx.x; t < TOTB; t += 256) {
        int c = lh[t];
        if (c) { lbase[t] = atomicAdd(&gcursor[t], c); lh[t] = 0; }
    }
    __syncthreads();
    for (int t = threadIdx.x; t < CHUNK; t += 256) {
        int e = e0 + t;
        if (e < E) {
            int d = dst[e];
            int bin = bb + (d >> BSH);
            int p = atomicAdd(&lh[bin], 1);
            binned[lbase[bin] + p] = (srcp[e] << BSH) | (d & (BINW - 1));
        }
    }
}

// ---------------------------------------------------------------------------
// Pass D: per-bin exact CSR
struct BinMeta { int relbase[NREL + 1]; int* off[NREL]; int ndst[NREL]; };
__global__ __launch_bounds__(256) void csrD_kernel(BinMeta bmt, const int* __restrict__ gbinstart,
                                                   const int* __restrict__ binned,
                                                   int* __restrict__ adj) {
    __shared__ int lcnt[BINW], lexc[BINW];
    int b = blockIdx.x, j = 0;
    while (b >= bmt.relbase[j + 1]) ++j;
    int lb = b - bmt.relbase[j];
    int n0 = lb << BSH;
    int nn = bmt.ndst[j] - n0; if (nn > BINW) nn = BINW;
    int es = gbinstart[b], ee = gbinstart[b + 1];
    for (int t = threadIdx.x; t < BINW; t += 256) lcnt[t] = 0;
    __syncthreads();
    for (int t = es + threadIdx.x; t < ee; t += 256)
        atomicAdd(&lcnt[binned[t] & (BINW - 1)], 1);
    __syncthreads();
    if (threadIdx.x < 64) {
        int lane = threadIdx.x, carry = 0;
        for (int base = 0; base < BINW; base += 64) {
            int v = lcnt[base + lane];
            int ts = v;
            for (int d = 1; d < 64; d <<= 1) { int t2 = __shfl_up(ts, d); if (lane >= d) ts += t2; }
            lexc[base + lane] = carry + ts - v;
            carry += __shfl(ts, 63);
        }
    }
    __syncthreads();
    int* off = bmt.off[j];
    for (int t = threadIdx.x; t < nn; t += 256) off[n0 + t] = es + lexc[t];
    if (threadIdx.x == 0 && n0 + nn == bmt.ndst[j]) off[bmt.ndst[j]] = ee;
    for (int t = threadIdx.x; t < BINW; t += 256) lcnt[t] = 0;
    __syncthreads();
    for (int t = es + threadIdx.x; t < ee; t += 256) {
        int v = binned[t];
        int dl = v & (BINW - 1);
        int p = atomicAdd(&lcnt[dl], 1);
        adj[es + lexc[dl] + p] = v >> BSH;
    }
}

// ---------------------------------------------------------------------------
// gather v2: packed-fp16 accumulate, 16B loads (8 lanes/row), two modes:
//   mode 0 (pair): 2 nodes/wave, 4 rowgroups/side, exact interior (no clamps)
//   mode 1 (oct):  8 nodes/wave, 1 rowgroup/node, no cross-lane reduce
struct GJob { const int* off; const uint4* x; uint4* cat; int cstr, colbase, n, mode; };
struct GatherJobs { GJob jb[6]; int blk_end[6]; };

__global__ __launch_bounds__(256) void gather_kernel(GatherJobs g, const int* __restrict__ adj) {
    int b = blockIdx.x, j = 0;
    while (b >= g.blk_end[j]) ++j;
    int b0 = j ? g.blk_end[j - 1] : 0;
    int nbk = g.blk_end[j] - b0;
    GJob jb = g.jb[j];
    int tid = threadIdx.x, w = tid >> 6, lane = tid & 63;
    int cq = lane & 7, rg = lane >> 3;
    if (jb.mode == 0) {
        int side = rg >> 2, sub = rg & 3;
        int npair = (jb.n + 1) >> 1;
        for (int p = (b - b0) * 4 + w; p < npair; p += nbk * 4) {
            int ia = p * 2;
            bool hb = (ia + 1 < jb.n);
            int a0 = jb.off[ia], a1 = jb.off[ia + 1];
            int b1 = hb ? jb.off[ia + 2] : a1;
            int cnt = side ? (b1 - a1) : (a1 - a0);
            const int* base = adj + (side ? a1 : a0);
            half8 acc = {0, 0, 0, 0, 0, 0, 0, 0};
            int full = cnt & ~3;
            for (int e = sub; e < full; e += 4) {
                int idx = base[e];
                acc += *(const half8*)(jb.x + (long long)idx * 8 + cq);
            }
            int e = full + sub;
            if (e < cnt) {
                int idx = base[e];
                acc += *(const half8*)(jb.x + (long long)idx * 8 + cq);
            }
            // reduce across the 4 rowgroups within each side
            uint4 u = __builtin_bit_cast(uint4, acc), o;
            o.x = __shfl_xor((int)u.x, 8); o.y = __shfl_xor((int)u.y, 8);
            o.z = __shfl_xor((int)u.z, 8); o.w = __shfl_xor((int)u.w, 8);
            acc += __builtin_bit_cast(half8, o);
            u = __builtin_bit_cast(uint4, acc);
            o.x = __shfl_xor((int)u.x, 16); o.y = __shfl_xor((int)u.y, 16);
            o.z = __shfl_xor((int)u.z, 16); o.w = __shfl_xor((int)u.w, 16);
            acc += __builtin_bit_cast(half8, o);
            float invf = 1.f / fmaxf((float)cnt, 1.f);
            _Float16 ih = (_Float16)invf;
            half8 iv = {ih, ih, ih, ih, ih, ih, ih, ih};
            acc *= iv;
            if (sub == 0 && (side == 0 || hb)) {
                int node = ia + side;
                jb.cat[(long long)node * jb.cstr + jb.colbase + cq] =
                    __builtin_bit_cast(uint4, acc);
            }
        }
    } else {
        for (int gp = (b - b0) * 4 + w; gp * 8 < jb.n; gp += nbk * 4) {
            int node = gp * 8 + rg;
            int nc = node < jb.n ? node : jb.n - 1;
            int o0 = jb.off[nc], o1 = jb.off[nc + 1];
            int cnt = (node < jb.n) ? (o1 - o0) : 0;
            half8 acc = {0, 0, 0, 0, 0, 0, 0, 0};
            for (int t = 0; t < cnt; ++t) {
                int idx = adj[o0 + t];
                acc += *(const half8*)(jb.x + (long long)idx * 8 + cq);
            }
            float invf = 1.f / fmaxf((float)cnt, 1.f);
            _Float16 ih = (_Float16)invf;
            half8 iv = {ih, ih, ih, ih, ih, ih, ih, ih};
            acc *= iv;
            if (node < jb.n)
                jb.cat[(long long)node * jb.cstr + jb.colbase + cq] =
                    __builtin_bit_cast(uint4, acc);
        }
    }
}

// ---------------------------------------------------------------------------
// apply mega-kernel: out = cat @ [WmA;WmB] + xroot @ Wr + b via MFMA 16x16x32.
struct ApplyJobs {
    const uint4* cat[4]; const uint4* xr[4]; const uint4* Bimg[4];
    const float* bA[4]; const float* bB[4];
    ushort* out[4];
    int cat_kt[4]; int cstr4[4]; int n[4]; int relu[4]; int blk_end[4];
};
__global__ __launch_bounds__(256) void apply_kernel(ApplyJobs a, int njobs) {
    int b = blockIdx.x, j = 0;
    while (b >= a.blk_end[j]) ++j;
    int b0 = j ? a.blk_end[j - 1] : 0;
    int jb = a.blk_end[j] - b0;
    int n = a.n[j], cat_kt = a.cat_kt[j], cstr4 = a.cstr4[j], relu = a.relu[j];
    int K_kt = cat_kt + 2;
    const uint4* cat = a.cat[j];
    const uint4* xr = a.xr[j];
    const uint4* Bimg = a.Bimg[j];
    const float* bA = a.bA[j];
    const float* bB = a.bB[j];
    ushort* out = a.out[j];
    int tid = threadIdx.x;
    int w = tid >> 6, lane = tid & 63;
    int mrow = lane & 15, koct = lane >> 4;
    int tiles = (n + 15) >> 4;
    for (int t = (b - b0) * 4 + w; t < tiles; t += jb * 4) {
        int m0 = t << 4;
        int row = m0 + mrow;
        if (row > n - 1) row = n - 1;
        f32x4 acc0 = {0.f, 0.f, 0.f, 0.f};
        f32x4 acc1 = {0.f, 0.f, 0.f, 0.f};
        f32x4 acc2 = {0.f, 0.f, 0.f, 0.f};
        f32x4 acc3 = {0.f, 0.f, 0.f, 0.f};
        for (int kt = 0; kt < K_kt; ++kt) {
            uint4 av;
            if (kt < cat_kt) av = cat[(long long)row * cstr4 + kt * 4 + koct];
            else av = xr[(long long)row * 8 + (kt - cat_kt) * 4 + koct];
            half8 af = __builtin_bit_cast(half8, av);
            const uint4* bp = Bimg + kt * 256 + lane;
            half8 b0f = __builtin_bit_cast(half8, bp[0]);
            half8 b1f = __builtin_bit_cast(half8, bp[64]);
            half8 b2f = __builtin_bit_cast(half8, bp[128]);
            half8 b3f = __builtin_bit_cast(half8, bp[192]);
            acc0 = __builtin_amdgcn_mfma_f32_16x16x32_f16(af, b0f, acc0, 0, 0, 0);
            acc1 = __builtin_amdgcn_mfma_f32_16x16x32_f16(af, b1f, acc1, 0, 0, 0);
            acc2 = __builtin_amdgcn_mfma_f32_16x16x32_f16(af, b2f, acc2, 0, 0, 0);
            acc3 = __builtin_amdgcn_mfma_f32_16x16x32_f16(af, b3f, acc3, 0, 0, 0);
        }
        int c = lane & 15, r0 = m0 + (lane >> 4) * 4;
        f32x4 accs[4] = {acc0, acc1, acc2, acc3};
#pragma unroll
        for (int nt = 0; nt < 4; ++nt) {
            int col = nt * 16 + c;
            float bias = bA[col] + (bB ? bB[col] : 0.f);
#pragma unroll
            for (int r = 0; r < 4; ++r) {
                int rw = r0 + r;
                if (rw < n) {
                    float v = accs[nt][r] + bias;
                    if (relu) v = fmaxf(v, 0.f);
                    out[(long long)rw * 64 + col] = __builtin_bit_cast(ushort, (_Float16)v);
                }
            }
        }
    }
}

// ---------------------------------------------------------------------------
// classifier on fp16 tables with packed Wc1 + dot2
__global__ __launch_bounds__(256) void classifier_kernel(
        const ushort* __restrict__ xc, const ushort* __restrict__ xg,
        const int* __restrict__ pd, const int* __restrict__ pg,
        const uint2* __restrict__ gW1, const float* __restrict__ bc1,
        const float* __restrict__ Wc2, const float* __restrict__ bc2,
        float* __restrict__ out, int n) {
    __shared__ uint2 sW1[2048];
    __shared__ float sW2[256];
    __shared__ uint2 shp[4][32];
    __shared__ float sh1[4][65];
    int tid = threadIdx.x;
    for (int t = tid; t < 2048; t += 256) sW1[t] = gW1[t];
    if (tid < 256) sW2[tid] = Wc2[tid];
    __syncthreads();
    int lane = tid & 63, sub = tid >> 6;
    float b1 = bc1[lane];
    const uint* xcp = (const uint*)xc;
    const uint* xgp = (const uint*)xg;
    for (int base = blockIdx.x * 4; base < n; base += gridDim.x * 4) {
        int p = base + sub;
        if (p >= n) continue;
        int dp = pd[p], gp = pg[p];
        uint v = (lane < 32) ? xcp[(long long)dp * 32 + lane]
                             : xgp[(long long)gp * 32 + (lane - 32)];
        ((uint*)&shp[sub][0])[lane] = v;
        float acc = b1;
#pragma unroll
        for (int k4 = 0; k4 < 32; ++k4) {
            uint2 wv = sW1[k4 * 64 + lane];
            uint2 mv = shp[sub][k4];
            acc = fdot2u(mv.x, wv.x, acc);
            acc = fdot2u(mv.y, wv.y, acc);
        }
        sh1[sub][lane] = fmaxf(acc, 0.f);
        if (lane < 4) {
            float a2 = bc2[lane];
#pragma unroll 16
            for (int k = 0; k < 64; ++k) a2 += sh1[sub][k] * sW2[k * 4 + lane];
            out[(long long)p * 4 + lane] = a2;
        }
    }
}

// ---------------------------------------------------------------------------
extern "C" void kernel_launch(void* const* d_in, const int* in_sizes, int n_in,
                              void* d_out, int out_size, void* d_ws, size_t ws_size,
                              hipStream_t stream) {
    const float* gene = (const float*)d_in[0];
    const float* drug = (const float*)d_in[1];
    const float* pcls = (const float*)d_in[2];
    const float* famb = (const float*)d_in[3];
    const float* Wm   = (const float*)d_in[4];
    const float* bm   = (const float*)d_in[5];
    const float* Wr   = (const float*)d_in[6];
    const float* Wc1  = (const float*)d_in[7];
    const float* bc1  = (const float*)d_in[8];
    const float* Wc2  = (const float*)d_in[9];
    const float* bc2  = (const float*)d_in[10];
    const int* ecg_s = (const int*)d_in[11];
    const int* ecg_d = (const int*)d_in[12];
    const int* egc_s = (const int*)d_in[13];
    const int* egc_d = (const int*)d_in[14];
    const int* ecp_s = (const int*)d_in[15];
    const int* ecp_d = (const int*)d_in[16];
    const int* epc_s = (const int*)d_in[17];
    const int* epc_d = (const int*)d_in[18];
    const int* egf_s = (const int*)d_in[19];
    const int* egf_d = (const int*)d_in[20];
    const int* efg_s = (const int*)d_in[21];
    const int* efg_d = (const int*)d_in[22];
    const int* pair_d = (const int*)d_in[23];
    const int* pair_g = (const int*)d_in[24];
    const int E_CG = in_sizes[11];
    const int E_CP = in_sizes[15];
    const int E_GF = in_sizes[19];
    const int N_PAIRS = in_sizes[23];
    const long long TOT_E = 2LL * E_CG + 2LL * E_CP + 2LL * E_GF;

    // ---- workspace layout ----
    ushort* g16   = (ushort*)d_ws;                       // also x2g
    ushort* d16   = g16   + (long long)NG * DD;          // also x2c
    ushort* p16   = d16   + (long long)ND * DD;
    ushort* f16b  = p16   + (long long)NC * DD;
    ushort* x1g16 = f16b  + (long long)NF * DD;
    ushort* x1c16 = x1g16 + (long long)NG * DD;
    ushort* x1p16 = x1c16 + (long long)ND * DD;
    ushort* x1f16 = x1p16 + (long long)NC * DD;
    ushort* x2g16 = g16;
    ushort* x2c16 = d16;
    uint2* pwWc1 = (uint2*)(x1f16 + (long long)NF * DD); // 2048 uint2
    uint4* bimg = (uint4*)(pwWc1 + 2048);                // 6*1536 uint4
    int* ghist = (int*)(bimg + 6 * 1536);                // TOTB
    int* gbinstart = ghist + TOTB;                       // TOTB+1
    int* gcursor = gbinstart + TOTB + 1;                 // TOTB
    int* off_cg = gcursor + TOTB;                        // NG+1
    int* off_gc = off_cg + NG + 1;
    int* off_cp = off_gc + ND + 1;
    int* off_pc = off_cp + NC + 1;
    int* off_gf = off_pc + ND + 1;
    int* off_fg = off_gf + NF + 1;
    long long binned_off = (long long)(off_fg + NG + 1 - (int*)d_ws);
    binned_off = (binned_off + 3) & ~3LL;                // 16B align
    int* binned = (int*)d_ws + binned_off;               // TOT_E ints
    int* adj    = binned + TOT_E;                        // TOT_E ints
    // cat buffers: cat_c/p/f alias binned (dead after csrD); cat_g after adj
    uint4* cat_c = (uint4*)binned;                       // ND*16
    uint4* cat_p = cat_c + (long long)ND * 16;           // NC*8
    uint4* cat_f = cat_p + (long long)NC * 8;            // NF*8
    uint4* cat_g = (uint4*)(adj + TOT_E);                // NG*16

    auto WmLR = [&](int l, int r) { return Wm + (long long)(l * 6 + r) * DD * DD; };
    auto WrLR = [&](int l, int r) { return Wr + (long long)(l * 6 + r) * DD * DD; };
    auto bmLR = [&](int l, int r) { return bm + (long long)(l * 6 + r) * DD; };

    // ---- edge jobs ----
    EdgeJobs ej;
    const int* srcs[NREL] = {ecg_s, egc_s, ecp_s, epc_s, egf_s, efg_s};
    const int* dsts[NREL] = {ecg_d, egc_d, ecp_d, epc_d, egf_d, efg_d};
    int Es[NREL] = {E_CG, E_CG, E_CP, E_CP, E_GF, E_GF};
    int bb[NREL] = {0, NB_CG, NB_CG + NB_GC, NB_CG + NB_GC + NB_CP,
                    NB_CG + NB_GC + NB_CP + NB_PC, NB_CG + NB_GC + NB_CP + NB_PC + NB_GF};
    int acc_blocks = 0;
    for (int j = 0; j < NREL; ++j) {
        ej.src[j] = srcs[j]; ej.dst[j] = dsts[j];
        ej.E[j] = Es[j]; ej.binbase[j] = bb[j];
        acc_blocks += (Es[j] + CHUNK - 1) / CHUNK;
        ej.blk_end[j] = acc_blocks;
    }
    const int THIST = acc_blocks;
    const int CVTB = 1024;

    // ---- pass A: hist + cvt + packs ----
    hipMemsetAsync(ghist, 0, TOTB * sizeof(int), stream);
    MegaA ma;
    ma.ej = ej;
    ma.cv.in[0] = gene; ma.cv.out[0] = (uint*)g16;  ma.cv.n2[0] = NG * DD / 2;
    ma.cv.in[1] = drug; ma.cv.out[1] = (uint*)d16;  ma.cv.n2[1] = ND * DD / 2;
    ma.cv.in[2] = pcls; ma.cv.out[2] = (uint*)p16;  ma.cv.n2[2] = NC * DD / 2;
    ma.cv.in[3] = famb; ma.cv.out[3] = (uint*)f16b; ma.cv.n2[3] = NF * DD / 2;
    ma.Wc1 = Wc1; ma.pwWc1 = pwWc1;
    auto setbp = [&](int j, const float* A, const float* B, const float* Ra, const float* Rb, int nkt) {
        ma.bp.A[j] = A; ma.bp.B[j] = B; ma.bp.Ra[j] = Ra; ma.bp.Rb[j] = Rb;
        ma.bp.out[j] = bimg + j * 1536; ma.bp.nkt[j] = nkt;
    };
    setbp(0, WmLR(0, 0), WmLR(0, 5), WrLR(0, 0), WrLR(0, 5), 6);
    setbp(1, WmLR(0, 1), WmLR(0, 3), WrLR(0, 1), WrLR(0, 3), 6);
    setbp(2, WmLR(0, 2), nullptr,    WrLR(0, 2), nullptr,    4);
    setbp(3, WmLR(0, 4), nullptr,    WrLR(0, 4), nullptr,    4);
    setbp(4, WmLR(1, 0), WmLR(1, 5), WrLR(1, 0), WrLR(1, 5), 6);
    setbp(5, WmLR(1, 1), WmLR(1, 3), WrLR(1, 1), WrLR(1, 3), 6);
    ma.hist_blocks = THIST; ma.cvt_blocks = CVTB;
    ma.ghist = ghist;
    megaA_kernel<<<THIST + CVTB + 1 + 6, 256, 0, stream>>>(ma);

    // ---- passes B, C, D ----
    scanB_kernel<<<1, 64, 0, stream>>>(ghist, gbinstart, gcursor);
    scatC_kernel<<<THIST, 256, 0, stream>>>(ej, gcursor, binned);
    BinMeta bmt;
    int rb[NREL + 1] = {0, NB_CG, NB_CG + NB_GC, NB_CG + NB_GC + NB_CP,
                        NB_CG + NB_GC + NB_CP + NB_PC,
                        NB_CG + NB_GC + NB_CP + NB_PC + NB_GF, TOTB};
    int* offs[NREL] = {off_cg, off_gc, off_cp, off_pc, off_gf, off_fg};
    int nds[NREL] = {NG, ND, NC, ND, NF, NG};
    for (int j = 0; j <= NREL; ++j) bmt.relbase[j] = rb[j];
    for (int j = 0; j < NREL; ++j) { bmt.off[j] = offs[j]; bmt.ndst[j] = nds[j]; }
    csrD_kernel<<<TOTB, 256, 0, stream>>>(bmt, gbinstart, binned, adj);

    auto ablk = [](int n) { int b = ((n + 15) / 16 + 3) / 4; return b > 1024 ? 1024 : b; };
    auto gb = [](int E) { int b = E / 1024; if (b < 8) b = 8; if (b > 2048) b = 2048; return b; };

    // ---- layer 0: gather then apply ----
    {
        GatherJobs g;
        int acc = 0;
        auto setg = [&](int j, const int* off, const ushort* x, uint4* cat,
                        int cstr, int colbase, int n, int mode, int E) {
            g.jb[j].off = off; g.jb[j].x = (const uint4*)x; g.jb[j].cat = cat;
            g.jb[j].cstr = cstr; g.jb[j].colbase = colbase; g.jb[j].n = n; g.jb[j].mode = mode;
            acc += gb(E); g.blk_end[j] = acc;
        };
        setg(0, off_cg, d16,  cat_g, 16, 0, NG, 0, E_CG);
        setg(1, off_fg, f16b, cat_g, 16, 8, NG, 1, E_GF);
        setg(2, off_gc, g16,  cat_c, 16, 0, ND, 0, E_CG);
        setg(3, off_pc, p16,  cat_c, 16, 8, ND, 1, E_CP);
        setg(4, off_cp, d16,  cat_p, 8, 0, NC, 0, E_CP);
        setg(5, off_gf, g16,  cat_f, 8, 0, NF, 0, E_GF);
        gather_kernel<<<acc, 256, 0, stream>>>(g, adj);

        ApplyJobs ap;
        auto seta = [&](int j, const uint4* cat, int ckt, int cstr4, const ushort* xr,
                        const uint4* Bi, const float* biA, const float* biB,
                        ushort* out, int n, int relu) {
            ap.cat[j] = cat; ap.cat_kt[j] = ckt; ap.cstr4[j] = cstr4;
            ap.xr[j] = (const uint4*)xr; ap.Bimg[j] = Bi; ap.bA[j] = biA; ap.bB[j] = biB;
            ap.out[j] = out; ap.n[j] = n; ap.relu[j] = relu;
        };
        seta(0, cat_g, 4, 16, g16,  bimg + 0 * 1536, bmLR(0, 0), bmLR(0, 5), x1g16, NG, 1);
        seta(1, cat_c, 4, 16, d16,  bimg + 1 * 1536, bmLR(0, 1), bmLR(0, 3), x1c16, ND, 1);
        seta(2, cat_p, 2, 8,  p16,  bimg + 2 * 1536, bmLR(0, 2), nullptr,    x1p16, NC, 1);
        seta(3, cat_f, 2, 8,  f16b, bimg + 3 * 1536, bmLR(0, 4), nullptr,    x1f16, NF, 1);
        int acc2 = 0;
        for (int j = 0; j < 4; ++j) { acc2 += ablk(ap.n[j]); ap.blk_end[j] = acc2; }
        apply_kernel<<<acc2, 256, 0, stream>>>(ap, 4);
    }

    // ---- layer 1: gather then apply (gene & compound only) ----
    {
        GatherJobs g;
        int acc = 0;
        auto setg = [&](int j, const int* off, const ushort* x, uint4* cat,
                        int cstr, int colbase, int n, int mode, int E) {
            g.jb[j].off = off; g.jb[j].x = (const uint4*)x; g.jb[j].cat = cat;
            g.jb[j].cstr = cstr; g.jb[j].colbase = colbase; g.jb[j].n = n; g.jb[j].mode = mode;
            acc += gb(E); g.blk_end[j] = acc;
        };
        setg(0, off_cg, x1c16, cat_g, 16, 0, NG, 0, E_CG);
        setg(1, off_fg, x1f16, cat_g, 16, 8, NG, 1, E_GF);
        setg(2, off_gc, x1g16, cat_c, 16, 0, ND, 0, E_CG);
        setg(3, off_pc, x1p16, cat_c, 16, 8, ND, 1, E_CP);
        // unused slots
        g.jb[4] = g.jb[3]; g.jb[4].n = 0; g.blk_end[4] = acc;
        g.jb[5] = g.jb[3]; g.jb[5].n = 0; g.blk_end[5] = acc;
        gather_kernel<<<acc, 256, 0, stream>>>(g, adj);

        ApplyJobs ap;
        ap.cat[0] = cat_g; ap.cat_kt[0] = 4; ap.cstr4[0] = 16;
        ap.xr[0] = (const uint4*)x1g16; ap.Bimg[0] = bimg + 4 * 1536;
        ap.bA[0] = bmLR(1, 0); ap.bB[0] = bmLR(1, 5);
        ap.out[0] = x2g16; ap.n[0] = NG; ap.relu[0] = 0;
        ap.cat[1] = cat_c; ap.cat_kt[1] = 4; ap.cstr4[1] = 16;
        ap.xr[1] = (const uint4*)x1c16; ap.Bimg[1] = bimg + 5 * 1536;
        ap.bA[1] = bmLR(1, 1); ap.bB[1] = bmLR(1, 3);
        ap.out[1] = x2c16; ap.n[1] = ND; ap.relu[1] = 0;
        for (int j = 2; j < 4; ++j) { ap.cat[j] = nullptr; ap.xr[j] = nullptr; ap.Bimg[j] = nullptr; ap.bA[j] = nullptr; ap.bB[j] = nullptr; ap.out[j] = nullptr; ap.n[j] = 0; ap.relu[j] = 0; ap.cat_kt[j] = 2; ap.cstr4[j] = 8; }
        int acc2 = ablk(NG); ap.blk_end[0] = acc2; acc2 += ablk(ND); ap.blk_end[1] = acc2;
        ap.blk_end[2] = acc2; ap.blk_end[3] = acc2;
        apply_kernel<<<acc2, 256, 0, stream>>>(ap, 2);
    }

    // ---- classifier ----
    int cblocks = (N_PAIRS + 3) / 4;
    if (cblocks > 2048) cblocks = 2048;
    classifier_kernel<<<cblocks, 256, 0, stream>>>(x2c16, x2g16, pair_d, pair_g,
                                                   pwWc1, bc1, Wc2, bc2,
                                                   (float*)d_out, N_PAIRS);
}

// Round 11
// 485.997 us; speedup vs baseline: 1.0049x; 1.0049x over previous
//
#include <hip/hip_runtime.h>
#include <hip/hip_bf16.h>

#define NG 100000
#define ND 50000
#define NC 2000
#define NF 5000
#define DD 64

#define BSH 9
#define BINW 512
#define NREL 6
#define NB_CG ((NG + BINW - 1) / BINW)
#define NB_GC ((ND + BINW - 1) / BINW)
#define NB_CP ((NC + BINW - 1) / BINW)
#define NB_PC ((ND + BINW - 1) / BINW)
#define NB_GF ((NF + BINW - 1) / BINW)
#define NB_FG ((NG + BINW - 1) / BINW)
#define TOTB (NB_CG + NB_GC + NB_CP + NB_PC + NB_GF + NB_FG)
#define CHUNK 4096

typedef _Float16 h2_t __attribute__((ext_vector_type(2)));
typedef _Float16 half8 __attribute__((ext_vector_type(8)));
typedef float f32x4 __attribute__((ext_vector_type(4)));
typedef float f32x2 __attribute__((ext_vector_type(2)));
typedef unsigned char uchar;

__device__ inline uint packh2_rne(float a, float b) {
    h2_t h; h.x = (_Float16)a; h.y = (_Float16)b;
    return __builtin_bit_cast(uint, h);
}
__device__ inline uint packh2(float a, float b) {  // RTZ, 1 instr
    return __builtin_bit_cast(uint, __builtin_amdgcn_cvt_pkrtz(a, b));
}
__device__ inline float2 h2f2(uint u) {
    h2_t h = __builtin_bit_cast(h2_t, u);
    return make_float2((float)h.x, (float)h.y);
}
__device__ inline float fdot2u(uint m, uint w, float acc) {
#if __has_builtin(__builtin_amdgcn_fdot2)
    return __builtin_amdgcn_fdot2(__builtin_bit_cast(h2_t, m),
                                  __builtin_bit_cast(h2_t, w), acc, false);
#else
    float2 a = h2f2(m), b = h2f2(w);
    return acc + a.x * b.x + a.y * b.y;
#endif
}

// ---- fp8 e4m3: hardware cvt when available (device pass), sw fallback ----
#if __has_builtin(__builtin_amdgcn_cvt_pk_f32_fp8) && __has_builtin(__builtin_amdgcn_cvt_pk_fp8_f32)
template <bool HI>
__device__ inline f32x2 dec_pk8(uint u) {
    return __builtin_amdgcn_cvt_pk_f32_fp8(u, HI);
}
__device__ inline uint enc2_fp8(float a, float b) {
    return __builtin_amdgcn_cvt_pk_fp8_f32(a, b, 0u, false) & 0xffffu;
}
__device__ inline uint enc1_fp8(float a) {
    return __builtin_amdgcn_cvt_pk_fp8_f32(a, a, 0u, false) & 0xffu;
}
#else
template <bool HI>
__device__ inline f32x2 dec_pk8(uint u) {
    uint pair = HI ? (u >> 16) : (u & 0xffffu);
    uint b0 = pair & 0xffu, b1 = (pair >> 8) & 0xffu;
    ushort h0 = (ushort)(((b0 & 0x80u) << 8) | ((b0 & 0x7fu) << 7));
    ushort h1 = (ushort)(((b1 & 0x80u) << 8) | ((b1 & 0x7fu) << 7));
    f32x2 r;
    r.x = 256.f * (float)__builtin_bit_cast(_Float16, h0);
    r.y = 256.f * (float)__builtin_bit_cast(_Float16, h1);
    return r;
}
__device__ inline uint enc1_fp8(float x) {
    ushort h = __builtin_bit_cast(ushort, (_Float16)(x * 0.00390625f));
    uint mag = h & 0x7fffu;
    uint r = (mag + 0x3fu + ((mag >> 7) & 1u)) >> 7;
    if (r > 0x7eu) r = 0x7eu;
    return r | ((h >> 8) & 0x80u);
}
__device__ inline uint enc2_fp8(float a, float b) {
    return enc1_fp8(a) | (enc1_fp8(b) << 8);
}
#endif

// ---------------------------------------------------------------------------
struct Cvt4 { const float* in[4]; uint* out[4]; ushort* out8[4]; int n2[4]; };
struct EdgeJobs {
    const int* src[NREL]; const int* dst[NREL];
    int binbase[NREL]; int E[NREL]; int blk_end[NREL];
};
struct BPackJobs {
    const float* A[6]; const float* B[6]; const float* Ra[6]; const float* Rb[6];
    uint4* out[6]; int nkt[6];
};

// ---------------------------------------------------------------------------
// Mega pass A: edge bin-histogram | f32->{f16,fp8} table cvt | Wc1 pack |
// MFMA B-image packs.
struct MegaA {
    EdgeJobs ej; Cvt4 cv; BPackJobs bp;
    const float* Wc1; uint2* pwWc1;
    int hist_blocks, cvt_blocks;
    int* ghist;
};
__global__ __launch_bounds__(256) void megaA_kernel(MegaA a) {
    int b = blockIdx.x;
    if (b < a.hist_blocks) {
        __shared__ int lh[TOTB];
        for (int t = threadIdx.x; t < TOTB; t += 256) lh[t] = 0;
        __syncthreads();
        int j = 0;
        while (b >= a.ej.blk_end[j]) ++j;
        int b0 = j ? a.ej.blk_end[j - 1] : 0;
        int e0 = (b - b0) * CHUNK;
        const int* dst = a.ej.dst[j];
        int E = a.ej.E[j], bb = a.ej.binbase[j];
        for (int t = threadIdx.x; t < CHUNK; t += 256) {
            int e = e0 + t;
            if (e < E) atomicAdd(&lh[bb + (dst[e] >> BSH)], 1);
        }
        __syncthreads();
        for (int t = threadIdx.x; t < TOTB; t += 256)
            if (lh[t]) atomicAdd(&a.ghist[t], lh[t]);
    } else if (b < a.hist_blocks + a.cvt_blocks) {
        int cb = b - a.hist_blocks;
        for (int j = 0; j < 4; ++j) {
            int n2 = a.cv.n2[j];
            const float2* ip = (const float2*)a.cv.in[j];
            uint* op = a.cv.out[j];
            ushort* o8 = a.cv.out8[j];
            for (int i = cb * 256 + threadIdx.x; i < n2; i += a.cvt_blocks * 256) {
                float2 v = ip[i];
                op[i] = packh2_rne(v.x, v.y);
                if (o8) o8[i] = (ushort)enc2_fp8(v.x, v.y);
            }
        }
    } else if (b == a.hist_blocks + a.cvt_blocks) {
        const float* A = a.Wc1;
        uint2* o = a.pwWc1;
        for (int t = threadIdx.x; t < 32 * 64; t += 256) {
            int k4 = t >> 6, c = t & 63;
            float v0 = A[(4 * k4 + 0) * 64 + c];
            float v1 = A[(4 * k4 + 1) * 64 + c];
            float v2 = A[(4 * k4 + 2) * 64 + c];
            float v3 = A[(4 * k4 + 3) * 64 + c];
            o[t] = make_uint2(packh2_rne(v0, v1), packh2_rne(v2, v3));
        }
    } else {
        int pj = b - a.hist_blocks - a.cvt_blocks - 1;
        const float* A = a.bp.A[pj];
        const float* B = a.bp.B[pj];
        const float* Ra = a.bp.Ra[pj];
        const float* Rb = a.bp.Rb[pj];
        uint4* o = a.bp.out[pj];
        int n = a.bp.nkt[pj] * 4 * 64;
        for (int t = threadIdx.x; t < n; t += 256) {
            int kt = t >> 8, nt = (t >> 6) & 3, l = t & 63;
            int col = nt * 16 + (l & 15);
            float v[8];
#pragma unroll
            for (int j = 0; j < 8; ++j) {
                int k = kt * 32 + ((l >> 4) << 3) + j;
                int sel = k >> 6, r = k & 63;
                float x;
                if (sel == 0) x = A[r * 64 + col];
                else if (sel == 1 && B) x = B[r * 64 + col];
                else x = Ra[r * 64 + col] + (Rb ? Rb[r * 64 + col] : 0.f);
                v[j] = x;
            }
            o[t] = make_uint4(packh2_rne(v[0], v[1]), packh2_rne(v[2], v[3]),
                              packh2_rne(v[4], v[5]), packh2_rne(v[6], v[7]));
        }
    }
}

// ---------------------------------------------------------------------------
// Pass B: exclusive scan of bin counts (1 block, wave 0)
__global__ void scanB_kernel(const int* __restrict__ ghist, int* __restrict__ gbinstart,
                             int* __restrict__ gcursor) {
    int lane = threadIdx.x;
    if (lane >= 64) return;
    int carry = 0;
    for (int base = 0; base < TOTB; base += 64) {
        int idx = base + lane;
        int v = (idx < TOTB) ? ghist[idx] : 0;
        int ts = v;
        for (int d = 1; d < 64; d <<= 1) { int t = __shfl_up(ts, d); if (lane >= d) ts += t; }
        int excl = carry + ts - v;
        if (idx < TOTB) { gbinstart[idx] = excl; gcursor[idx] = excl; }
        carry += __shfl(ts, 63);
    }
    if (lane == 0) gbinstart[TOTB] = carry;
}

// ---------------------------------------------------------------------------
// Pass C: binned scatter of packed (src<<9 | dstLocal)
__global__ __launch_bounds__(256) void scatC_kernel(EdgeJobs ej, int* __restrict__ gcursor,
                                                    int* __restrict__ binned) {
    __shared__ int lh[TOTB], lbase[TOTB];
    for (int t = threadIdx.x; t < TOTB; t += 256) lh[t] = 0;
    __syncthreads();
    int b = blockIdx.x, j = 0;
    while (b >= ej.blk_end[j]) ++j;
    int b0 = j ? ej.blk_end[j - 1] : 0;
    int e0 = (b - b0) * CHUNK;
    const int* dst = ej.dst[j];
    const int* srcp = ej.src[j];
    int E = ej.E[j], bb = ej.binbase[j];
    for (int t = threadIdx.x; t < CHUNK; t += 256) {
        int e = e0 + t;
        if (e < E) atomicAdd(&lh[bb + (dst[e] >> BSH)], 1);
    }
    __syncthreads();
    for (int t = threadIdx.x; t < TOTB; t += 256) {
        int c = lh[t];
        if (c) { lbase[t] = atomicAdd(&gcursor[t], c); lh[t] = 0; }
    }
    __syncthreads();
    for (int t = threadIdx.x; t < CHUNK; t += 256) {
        int e = e0 + t;
        if (e < E) {
            int d = dst[e];
            int bin = bb + (d >> BSH);
            int p = atomicAdd(&lh[bin], 1);
            binned[lbase[bin] + p] = (srcp[e] << BSH) | (d & (BINW - 1));
        }
    }
}

// ---------------------------------------------------------------------------
// Pass D: per-bin exact CSR
struct BinMeta { int relbase[NREL + 1]; int* off[NREL]; int ndst[NREL]; };
__global__ __launch_bounds__(256) void csrD_kernel(BinMeta bmt, const int* __restrict__ gbinstart,
                                                   const int* __restrict__ binned,
                                                   int* __restrict__ adj) {
    __shared__ int lcnt[BINW], lexc[BINW];
    int b = blockIdx.x, j = 0;
    while (b >= bmt.relbase[j + 1]) ++j;
    int lb = b - bmt.relbase[j];
    int n0 = lb << BSH;
    int nn = bmt.ndst[j] - n0; if (nn > BINW) nn = BINW;
    int es = gbinstart[b], ee = gbinstart[b + 1];
    for (int t = threadIdx.x; t < BINW; t += 256) lcnt[t] = 0;
    __syncthreads();
    for (int t = es + threadIdx.x; t < ee; t += 256)
        atomicAdd(&lcnt[binned[t] & (BINW - 1)], 1);
    __syncthreads();
    if (threadIdx.x < 64) {
        int lane = threadIdx.x, carry = 0;
        for (int base = 0; base < BINW; base += 64) {
            int v = lcnt[base + lane];
            int ts = v;
            for (int d = 1; d < 64; d <<= 1) { int t2 = __shfl_up(ts, d); if (lane >= d) ts += t2; }
            lexc[base + lane] = carry + ts - v;
            carry += __shfl(ts, 63);
        }
    }
    __syncthreads();
    int* off = bmt.off[j];
    for (int t = threadIdx.x; t < nn; t += 256) off[n0 + t] = es + lexc[t];
    if (threadIdx.x == 0 && n0 + nn == bmt.ndst[j]) off[bmt.ndst[j]] = ee;
    for (int t = threadIdx.x; t < BINW; t += 256) lcnt[t] = 0;
    __syncthreads();
    for (int t = es + threadIdx.x; t < ee; t += 256) {
        int v = binned[t];
        int dl = v & (BINW - 1);
        int p = atomicAdd(&lcnt[dl], 1);
        adj[es + lexc[dl] + p] = v >> BSH;
    }
}

// ---------------------------------------------------------------------------
// gather v4: mode 0 (pair, big tables): fp8-e4m3 rows (64 B), hw decode,
// f32 accumulate. mode 1 (oct, small tables): fp16 rows (128 B), pk-f16 acc.
struct GJob { const int* off; const void* x; uint4* cat; int cstr, colbase, n, mode; };
struct GatherJobs { GJob jb[6]; int blk_end[6]; };

__global__ __launch_bounds__(256) void gather_kernel(GatherJobs g, const int* __restrict__ adj) {
    int b = blockIdx.x, j = 0;
    while (b >= g.blk_end[j]) ++j;
    int b0 = j ? g.blk_end[j - 1] : 0;
    int nbk = g.blk_end[j] - b0;
    GJob jb = g.jb[j];
    int tid = threadIdx.x, w = tid >> 6, lane = tid & 63;
    int cq = lane & 7, rg = lane >> 3;
    if (jb.mode == 0) {
        const uint2* x8 = (const uint2*)jb.x;
        int side = rg >> 2, sub = rg & 3;
        int npair = (jb.n + 1) >> 1;
        for (int p = (b - b0) * 4 + w; p < npair; p += nbk * 4) {
            int ia = p * 2;
            bool hb = (ia + 1 < jb.n);
            int a0 = jb.off[ia], a1 = jb.off[ia + 1];
            int b1 = hb ? jb.off[ia + 2] : a1;
            int cnt = side ? (b1 - a1) : (a1 - a0);
            const int* base = adj + (side ? a1 : a0);
            float s0 = 0, s1 = 0, s2 = 0, s3 = 0, s4 = 0, s5 = 0, s6 = 0, s7 = 0;
            int full = cnt & ~3;
            for (int e = sub; e < full; e += 4) {
                uint2 v = x8[(long long)base[e] * 8 + cq];
                f32x2 p01 = dec_pk8<false>(v.x), p23 = dec_pk8<true>(v.x);
                f32x2 p45 = dec_pk8<false>(v.y), p67 = dec_pk8<true>(v.y);
                s0 += p01.x; s1 += p01.y; s2 += p23.x; s3 += p23.y;
                s4 += p45.x; s5 += p45.y; s6 += p67.x; s7 += p67.y;
            }
            int e = full + sub;
            if (e < cnt) {
                uint2 v = x8[(long long)base[e] * 8 + cq];
                f32x2 p01 = dec_pk8<false>(v.x), p23 = dec_pk8<true>(v.x);
                f32x2 p45 = dec_pk8<false>(v.y), p67 = dec_pk8<true>(v.y);
                s0 += p01.x; s1 += p01.y; s2 += p23.x; s3 += p23.y;
                s4 += p45.x; s5 += p45.y; s6 += p67.x; s7 += p67.y;
            }
            s0 += __shfl_xor(s0, 8);  s1 += __shfl_xor(s1, 8);
            s2 += __shfl_xor(s2, 8);  s3 += __shfl_xor(s3, 8);
            s4 += __shfl_xor(s4, 8);  s5 += __shfl_xor(s5, 8);
            s6 += __shfl_xor(s6, 8);  s7 += __shfl_xor(s7, 8);
            s0 += __shfl_xor(s0, 16); s1 += __shfl_xor(s1, 16);
            s2 += __shfl_xor(s2, 16); s3 += __shfl_xor(s3, 16);
            s4 += __shfl_xor(s4, 16); s5 += __shfl_xor(s5, 16);
            s6 += __shfl_xor(s6, 16); s7 += __shfl_xor(s7, 16);
            float invf = 1.f / fmaxf((float)cnt, 1.f);
            if (sub == 0 && (side == 0 || hb)) {
                int node = ia + side;
                uint4 o = make_uint4(packh2(s0 * invf, s1 * invf), packh2(s2 * invf, s3 * invf),
                                     packh2(s4 * invf, s5 * invf), packh2(s6 * invf, s7 * invf));
                jb.cat[(long long)node * jb.cstr + jb.colbase + cq] = o;
            }
        }
    } else {
        const uint4* x16 = (const uint4*)jb.x;
        for (int gp = (b - b0) * 4 + w; gp * 8 < jb.n; gp += nbk * 4) {
            int node = gp * 8 + rg;
            int nc = node < jb.n ? node : jb.n - 1;
            int o0 = jb.off[nc], o1 = jb.off[nc + 1];
            int cnt = (node < jb.n) ? (o1 - o0) : 0;
            half8 acc = {0, 0, 0, 0, 0, 0, 0, 0};
            for (int t = 0; t < cnt; ++t) {
                int idx = adj[o0 + t];
                acc += __builtin_bit_cast(half8, x16[(long long)idx * 8 + cq]);
            }
            float invf = 1.f / fmaxf((float)cnt, 1.f);
            _Float16 ih = (_Float16)invf;
            half8 iv = {ih, ih, ih, ih, ih, ih, ih, ih};
            acc *= iv;
            if (node < jb.n)
                jb.cat[(long long)node * jb.cstr + jb.colbase + cq] =
                    __builtin_bit_cast(uint4, acc);
        }
    }
}

// ---------------------------------------------------------------------------
// apply mega-kernel: out = cat @ [WmA;WmB] + xroot @ Wr + b via MFMA 16x16x32.
// Optional fp16 out and/or fp8-e4m3 out (for next layer's gather).
struct ApplyJobs {
    const uint4* cat[4]; const uint4* xr[4]; const uint4* Bimg[4];
    const float* bA[4]; const float* bB[4];
    ushort* out[4]; uchar* out8[4];
    int cat_kt[4]; int cstr4[4]; int n[4]; int relu[4]; int blk_end[4];
};
__global__ __launch_bounds__(256) void apply_kernel(ApplyJobs a, int njobs) {
    int b = blockIdx.x, j = 0;
    while (b >= a.blk_end[j]) ++j;
    int b0 = j ? a.blk_end[j - 1] : 0;
    int jb = a.blk_end[j] - b0;
    int n = a.n[j], cat_kt = a.cat_kt[j], cstr4 = a.cstr4[j], relu = a.relu[j];
    int K_kt = cat_kt + 2;
    const uint4* cat = a.cat[j];
    const uint4* xr = a.xr[j];
    const uint4* Bimg = a.Bimg[j];
    const float* bA = a.bA[j];
    const float* bB = a.bB[j];
    ushort* out = a.out[j];
    uchar* out8 = a.out8[j];
    int tid = threadIdx.x;
    int w = tid >> 6, lane = tid & 63;
    int mrow = lane & 15, koct = lane >> 4;
    int tiles = (n + 15) >> 4;
    for (int t = (b - b0) * 4 + w; t < tiles; t += jb * 4) {
        int m0 = t << 4;
        int row = m0 + mrow;
        if (row > n - 1) row = n - 1;
        f32x4 acc0 = {0.f, 0.f, 0.f, 0.f};
        f32x4 acc1 = {0.f, 0.f, 0.f, 0.f};
        f32x4 acc2 = {0.f, 0.f, 0.f, 0.f};
        f32x4 acc3 = {0.f, 0.f, 0.f, 0.f};
        for (int kt = 0; kt < K_kt; ++kt) {
            uint4 av;
            if (kt < cat_kt) av = cat[(long long)row * cstr4 + kt * 4 + koct];
            else av = xr[(long long)row * 8 + (kt - cat_kt) * 4 + koct];
            half8 af = __builtin_bit_cast(half8, av);
            const uint4* bp = Bimg + kt * 256 + lane;
            half8 b0f = __builtin_bit_cast(half8, bp[0]);
            half8 b1f = __builtin_bit_cast(half8, bp[64]);
            half8 b2f = __builtin_bit_cast(half8, bp[128]);
            half8 b3f = __builtin_bit_cast(half8, bp[192]);
            acc0 = __builtin_amdgcn_mfma_f32_16x16x32_f16(af, b0f, acc0, 0, 0, 0);
            acc1 = __builtin_amdgcn_mfma_f32_16x16x32_f16(af, b1f, acc1, 0, 0, 0);
            acc2 = __builtin_amdgcn_mfma_f32_16x16x32_f16(af, b2f, acc2, 0, 0, 0);
            acc3 = __builtin_amdgcn_mfma_f32_16x16x32_f16(af, b3f, acc3, 0, 0, 0);
        }
        int c = lane & 15, r0 = m0 + (lane >> 4) * 4;
        f32x4 accs[4] = {acc0, acc1, acc2, acc3};
#pragma unroll
        for (int nt = 0; nt < 4; ++nt) {
            int col = nt * 16 + c;
            float bias = bA[col] + (bB ? bB[col] : 0.f);
#pragma unroll
            for (int r = 0; r < 4; ++r) {
                int rw = r0 + r;
                if (rw < n) {
                    float v = accs[nt][r] + bias;
                    if (relu) v = fmaxf(v, 0.f);
                    if (out) out[(long long)rw * 64 + col] =
                        __builtin_bit_cast(ushort, (_Float16)v);
                    if (out8) out8[(long long)rw * 64 + col] = (uchar)enc1_fp8(v);
                }
            }
        }
    }
}

// ---------------------------------------------------------------------------
// classifier on fp16 tables with packed Wc1 + dot2
__global__ __launch_bounds__(256) void classifier_kernel(
        const ushort* __restrict__ xc, const ushort* __restrict__ xg,
        const int* __restrict__ pd, const int* __restrict__ pg,
        const uint2* __restrict__ gW1, const float* __restrict__ bc1,
        const float* __restrict__ Wc2, const float* __restrict__ bc2,
        float* __restrict__ out, int n) {
    __shared__ uint2 sW1[2048];
    __shared__ float sW2[256];
    __shared__ uint2 shp[4][32];
    __shared__ float sh1[4][65];
    int tid = threadIdx.x;
    for (int t = tid; t < 2048; t += 256) sW1[t] = gW1[t];
    if (tid < 256) sW2[tid] = Wc2[tid];
    __syncthreads();
    int lane = tid & 63, sub = tid >> 6;
    float b1 = bc1[lane];
    const uint* xcp = (const uint*)xc;
    const uint* xgp = (const uint*)xg;
    for (int base = blockIdx.x * 4; base < n; base += gridDim.x * 4) {
        int p = base + sub;
        if (p >= n) continue;
        int dp = pd[p], gp = pg[p];
        uint v = (lane < 32) ? xcp[(long long)dp * 32 + lane]
                             : xgp[(long long)gp * 32 + (lane - 32)];
        ((uint*)&shp[sub][0])[lane] = v;
        float acc = b1;
#pragma unroll
        for (int k4 = 0; k4 < 32; ++k4) {
            uint2 wv = sW1[k4 * 64 + lane];
            uint2 mv = shp[sub][k4];
            acc = fdot2u(mv.x, wv.x, acc);
            acc = fdot2u(mv.y, wv.y, acc);
        }
        sh1[sub][lane] = fmaxf(acc, 0.f);
        if (lane < 4) {
            float a2 = bc2[lane];
#pragma unroll 16
            for (int k = 0; k < 64; ++k) a2 += sh1[sub][k] * sW2[k * 4 + lane];
            out[(long long)p * 4 + lane] = a2;
        }
    }
}

// ---------------------------------------------------------------------------
extern "C" void kernel_launch(void* const* d_in, const int* in_sizes, int n_in,
                              void* d_out, int out_size, void* d_ws, size_t ws_size,
                              hipStream_t stream) {
    const float* gene = (const float*)d_in[0];
    const float* drug = (const float*)d_in[1];
    const float* pcls = (const float*)d_in[2];
    const float* famb = (const float*)d_in[3];
    const float* Wm   = (const float*)d_in[4];
    const float* bm   = (const float*)d_in[5];
    const float* Wr   = (const float*)d_in[6];
    const float* Wc1  = (const float*)d_in[7];
    const float* bc1  = (const float*)d_in[8];
    const float* Wc2  = (const float*)d_in[9];
    const float* bc2  = (const float*)d_in[10];
    const int* ecg_s = (const int*)d_in[11];
    const int* ecg_d = (const int*)d_in[12];
    const int* egc_s = (const int*)d_in[13];
    const int* egc_d = (const int*)d_in[14];
    const int* ecp_s = (const int*)d_in[15];
    const int* ecp_d = (const int*)d_in[16];
    const int* epc_s = (const int*)d_in[17];
    const int* epc_d = (const int*)d_in[18];
    const int* egf_s = (const int*)d_in[19];
    const int* egf_d = (const int*)d_in[20];
    const int* efg_s = (const int*)d_in[21];
    const int* efg_d = (const int*)d_in[22];
    const int* pair_d = (const int*)d_in[23];
    const int* pair_g = (const int*)d_in[24];
    const int E_CG = in_sizes[11];
    const int E_CP = in_sizes[15];
    const int E_GF = in_sizes[19];
    const int N_PAIRS = in_sizes[23];
    const long long TOT_E = 2LL * E_CG + 2LL * E_CP + 2LL * E_GF;

    // ---- workspace layout ----
    ushort* g16   = (ushort*)d_ws;                       // also x2g
    ushort* d16   = g16   + (long long)NG * DD;          // also x2c
    ushort* p16   = d16   + (long long)ND * DD;
    ushort* f16b  = p16   + (long long)NC * DD;
    ushort* x1g16 = f16b  + (long long)NF * DD;
    ushort* x1c16 = x1g16 + (long long)NG * DD;
    ushort* x1p16 = x1c16 + (long long)ND * DD;
    ushort* x1f16 = x1p16 + (long long)NC * DD;
    ushort* x2g16 = g16;
    ushort* x2c16 = d16;
    uint2* pwWc1 = (uint2*)(x1f16 + (long long)NF * DD); // 2048 uint2
    uint4* bimg = (uint4*)(pwWc1 + 2048);                // 6*1536 uint4
    int* ghist = (int*)(bimg + 6 * 1536);                // TOTB
    int* gbinstart = ghist + TOTB;                       // TOTB+1
    int* gcursor = gbinstart + TOTB + 1;                 // TOTB
    int* off_cg = gcursor + TOTB;                        // NG+1
    int* off_gc = off_cg + NG + 1;
    int* off_cp = off_gc + ND + 1;
    int* off_pc = off_cp + NC + 1;
    int* off_gf = off_pc + ND + 1;
    int* off_fg = off_gf + NF + 1;
    long long binned_off = (long long)(off_fg + NG + 1 - (int*)d_ws);
    binned_off = (binned_off + 3) & ~3LL;                // 16B align
    int* binned = (int*)d_ws + binned_off;               // TOT_E ints
    int* adj    = binned + TOT_E;                        // TOT_E ints
    // cat_c/p/f alias binned (dead after csrD); cat_g after adj
    uint4* cat_c = (uint4*)binned;                       // ND*16
    uint4* cat_p = cat_c + (long long)ND * 16;           // NC*8
    uint4* cat_f = cat_p + (long long)NC * 8;            // NF*8
    uint4* cat_g = (uint4*)(adj + TOT_E);                // NG*16
    // fp8 tables after cat_g; x1 fp8 aliases them (inputs dead after L0 gather)
    uchar* g8  = (uchar*)(cat_g + (long long)NG * 16);   // NG*64
    uchar* d8v = g8  + (long long)NG * DD;               // ND*64
    uchar* x1g8 = g8;
    uchar* x1c8 = d8v;

    auto WmLR = [&](int l, int r) { return Wm + (long long)(l * 6 + r) * DD * DD; };
    auto WrLR = [&](int l, int r) { return Wr + (long long)(l * 6 + r) * DD * DD; };
    auto bmLR = [&](int l, int r) { return bm + (long long)(l * 6 + r) * DD; };

    // ---- edge jobs ----
    EdgeJobs ej;
    const int* srcs[NREL] = {ecg_s, egc_s, ecp_s, epc_s, egf_s, efg_s};
    const int* dsts[NREL] = {ecg_d, egc_d, ecp_d, epc_d, egf_d, efg_d};
    int Es[NREL] = {E_CG, E_CG, E_CP, E_CP, E_GF, E_GF};
    int bb[NREL] = {0, NB_CG, NB_CG + NB_GC, NB_CG + NB_GC + NB_CP,
                    NB_CG + NB_GC + NB_CP + NB_PC, NB_CG + NB_GC + NB_CP + NB_PC + NB_GF};
    int acc_blocks = 0;
    for (int j = 0; j < NREL; ++j) {
        ej.src[j] = srcs[j]; ej.dst[j] = dsts[j];
        ej.E[j] = Es[j]; ej.binbase[j] = bb[j];
        acc_blocks += (Es[j] + CHUNK - 1) / CHUNK;
        ej.blk_end[j] = acc_blocks;
    }
    const int THIST = acc_blocks;
    const int CVTB = 1024;

    // ---- pass A: hist + cvt (f16 + fp8 for gene/drug) + packs ----
    (void)hipMemsetAsync(ghist, 0, TOTB * sizeof(int), stream);
    MegaA ma;
    ma.ej = ej;
    ma.cv.in[0] = gene; ma.cv.out[0] = (uint*)g16;  ma.cv.out8[0] = (ushort*)g8;  ma.cv.n2[0] = NG * DD / 2;
    ma.cv.in[1] = drug; ma.cv.out[1] = (uint*)d16;  ma.cv.out8[1] = (ushort*)d8v; ma.cv.n2[1] = ND * DD / 2;
    ma.cv.in[2] = pcls; ma.cv.out[2] = (uint*)p16;  ma.cv.out8[2] = nullptr;      ma.cv.n2[2] = NC * DD / 2;
    ma.cv.in[3] = famb; ma.cv.out[3] = (uint*)f16b; ma.cv.out8[3] = nullptr;      ma.cv.n2[3] = NF * DD / 2;
    ma.Wc1 = Wc1; ma.pwWc1 = pwWc1;
    auto setbp = [&](int j, const float* A, const float* B, const float* Ra, const float* Rb, int nkt) {
        ma.bp.A[j] = A; ma.bp.B[j] = B; ma.bp.Ra[j] = Ra; ma.bp.Rb[j] = Rb;
        ma.bp.out[j] = bimg + j * 1536; ma.bp.nkt[j] = nkt;
    };
    setbp(0, WmLR(0, 0), WmLR(0, 5), WrLR(0, 0), WrLR(0, 5), 6);
    setbp(1, WmLR(0, 1), WmLR(0, 3), WrLR(0, 1), WrLR(0, 3), 6);
    setbp(2, WmLR(0, 2), nullptr,    WrLR(0, 2), nullptr,    4);
    setbp(3, WmLR(0, 4), nullptr,    WrLR(0, 4), nullptr,    4);
    setbp(4, WmLR(1, 0), WmLR(1, 5), WrLR(1, 0), WrLR(1, 5), 6);
    setbp(5, WmLR(1, 1), WmLR(1, 3), WrLR(1, 1), WrLR(1, 3), 6);
    ma.hist_blocks = THIST; ma.cvt_blocks = CVTB;
    ma.ghist = ghist;
    megaA_kernel<<<THIST + CVTB + 1 + 6, 256, 0, stream>>>(ma);

    // ---- passes B, C, D ----
    scanB_kernel<<<1, 64, 0, stream>>>(ghist, gbinstart, gcursor);
    scatC_kernel<<<THIST, 256, 0, stream>>>(ej, gcursor, binned);
    BinMeta bmt;
    int rb[NREL + 1] = {0, NB_CG, NB_CG + NB_GC, NB_CG + NB_GC + NB_CP,
                        NB_CG + NB_GC + NB_CP + NB_PC,
                        NB_CG + NB_GC + NB_CP + NB_PC + NB_GF, TOTB};
    int* offs[NREL] = {off_cg, off_gc, off_cp, off_pc, off_gf, off_fg};
    int nds[NREL] = {NG, ND, NC, ND, NF, NG};
    for (int j = 0; j <= NREL; ++j) bmt.relbase[j] = rb[j];
    for (int j = 0; j < NREL; ++j) { bmt.off[j] = offs[j]; bmt.ndst[j] = nds[j]; }
    csrD_kernel<<<TOTB, 256, 0, stream>>>(bmt, gbinstart, binned, adj);

    auto ablk = [](int n) { int b = ((n + 15) / 16 + 3) / 4; return b > 1024 ? 1024 : b; };
    auto gb = [](int E) { int b = E / 1024; if (b < 8) b = 8; if (b > 2048) b = 2048; return b; };

    // ---- layer 0: gather then apply ----
    {
        GatherJobs g;
        int acc = 0;
        auto setg = [&](int j, const int* off, const void* x, uint4* cat,
                        int cstr, int colbase, int n, int mode, int E) {
            g.jb[j].off = off; g.jb[j].x = x; g.jb[j].cat = cat;
            g.jb[j].cstr = cstr; g.jb[j].colbase = colbase; g.jb[j].n = n; g.jb[j].mode = mode;
            acc += gb(E); g.blk_end[j] = acc;
        };
        setg(0, off_cg, d8v,  cat_g, 16, 0, NG, 0, E_CG);
        setg(1, off_fg, f16b, cat_g, 16, 8, NG, 1, E_GF);
        setg(2, off_gc, g8,   cat_c, 16, 0, ND, 0, E_CG);
        setg(3, off_pc, p16,  cat_c, 16, 8, ND, 1, E_CP);
        setg(4, off_cp, d8v,  cat_p, 8, 0, NC, 0, E_CP);
        setg(5, off_gf, g8,   cat_f, 8, 0, NF, 0, E_GF);
        gather_kernel<<<acc, 256, 0, stream>>>(g, adj);

        ApplyJobs ap;
        auto seta = [&](int j, const uint4* cat, int ckt, int cstr4, const ushort* xr,
                        const uint4* Bi, const float* biA, const float* biB,
                        ushort* out, uchar* out8, int n, int relu) {
            ap.cat[j] = cat; ap.cat_kt[j] = ckt; ap.cstr4[j] = cstr4;
            ap.xr[j] = (const uint4*)xr; ap.Bimg[j] = Bi; ap.bA[j] = biA; ap.bB[j] = biB;
            ap.out[j] = out; ap.out8[j] = out8; ap.n[j] = n; ap.relu[j] = relu;
        };
        seta(0, cat_g, 4, 16, g16,  bimg + 0 * 1536, bmLR(0, 0), bmLR(0, 5), x1g16, x1g8, NG, 1);
        seta(1, cat_c, 4, 16, d16,  bimg + 1 * 1536, bmLR(0, 1), bmLR(0, 3), x1c16, x1c8, ND, 1);
        seta(2, cat_p, 2, 8,  p16,  bimg + 2 * 1536, bmLR(0, 2), nullptr,    x1p16, nullptr, NC, 1);
        seta(3, cat_f, 2, 8,  f16b, bimg + 3 * 1536, bmLR(0, 4), nullptr,    x1f16, nullptr, NF, 1);
        int acc2 = 0;
        for (int j = 0; j < 4; ++j) { acc2 += ablk(ap.n[j]); ap.blk_end[j] = acc2; }
        apply_kernel<<<acc2, 256, 0, stream>>>(ap, 4);
    }

    // ---- layer 1: gather then apply (gene & compound only) ----
    {
        GatherJobs g;
        int acc = 0;
        auto setg = [&](int j, const int* off, const void* x, uint4* cat,
                        int cstr, int colbase, int n, int mode, int E) {
            g.jb[j].off = off; g.jb[j].x = x; g.jb[j].cat = cat;
            g.jb[j].cstr = cstr; g.jb[j].colbase = colbase; g.jb[j].n = n; g.jb[j].mode = mode;
            acc += gb(E); g.blk_end[j] = acc;
        };
        setg(0, off_cg, x1c8,  cat_g, 16, 0, NG, 0, E_CG);
        setg(1, off_fg, x1f16, cat_g, 16, 8, NG, 1, E_GF);
        setg(2, off_gc, x1g8,  cat_c, 16, 0, ND, 0, E_CG);
        setg(3, off_pc, x1p16, cat_c, 16, 8, ND, 1, E_CP);
        g.jb[4] = g.jb[3]; g.jb[4].n = 0; g.blk_end[4] = acc;
        g.jb[5] = g.jb[3]; g.jb[5].n = 0; g.blk_end[5] = acc;
        gather_kernel<<<acc, 256, 0, stream>>>(g, adj);

        ApplyJobs ap;
        ap.cat[0] = cat_g; ap.cat_kt[0] = 4; ap.cstr4[0] = 16;
        ap.xr[0] = (const uint4*)x1g16; ap.Bimg[0] = bimg + 4 * 1536;
        ap.bA[0] = bmLR(1, 0); ap.bB[0] = bmLR(1, 5);
        ap.out[0] = x2g16; ap.out8[0] = nullptr; ap.n[0] = NG; ap.relu[0] = 0;
        ap.cat[1] = cat_c; ap.cat_kt[1] = 4; ap.cstr4[1] = 16;
        ap.xr[1] = (const uint4*)x1c16; ap.Bimg[1] = bimg + 5 * 1536;
        ap.bA[1] = bmLR(1, 1); ap.bB[1] = bmLR(1, 3);
        ap.out[1] = x2c16; ap.out8[1] = nullptr; ap.n[1] = ND; ap.relu[1] = 0;
        for (int j = 2; j < 4; ++j) {
            ap.cat[j] = nullptr; ap.xr[j] = nullptr; ap.Bimg[j] = nullptr;
            ap.bA[j] = nullptr; ap.bB[j] = nullptr; ap.out[j] = nullptr; ap.out8[j] = nullptr;
            ap.n[j] = 0; ap.relu[j] = 0; ap.cat_kt[j] = 2; ap.cstr4[j] = 8;
        }
        int acc2 = ablk(NG); ap.blk_end[0] = acc2; acc2 += ablk(ND); ap.blk_end[1] = acc2;
        ap.blk_end[2] = acc2; ap.blk_end[3] = acc2;
        apply_kernel<<<acc2, 256, 0, stream>>>(ap, 2);
    }

    // ---- classifier ----
    int cblocks = (N_PAIRS + 3) / 4;
    if (cblocks > 2048) cblocks = 2048;
    classifier_kernel<<<cblocks, 256, 0, stream>>>(x2c16, x2g16, pair_d, pair_g,
                                                   pwWc1, bc1, Wc2, bc2,
                                                   (float*)d_out, N_PAIRS);
}